// Round 4
// baseline (213.095 us; speedup 1.0000x reference)
//
#include <hip/hip_runtime.h>
#include <hip/hip_bf16.h>
#include <math.h>

#define NCLS 80
#define TOPK_N 1000
#define CAND_CAP 12288
#define T0 0.91f                // fast-path score threshold (exactness gated)
#define OBJ_T 1.55f             // obj pre-filter: sig(1.55)=0.8249 < T0^2=0.8281
                                // score>T0 ==> sig(obj)>T0^2 ==> obj>OBJ_T (safe margin)
#define NB 8192                 // fallback histogram bins = key >> 17
#define HREP 8                  // fallback histogram replicas
#define RBINS 3072              // rank bins (k4 counting sort)
#define RBIN_LO 0x3F680000u     // float bits of ~0.90625
#define ANCH_INV 524287         // 2^19-1, anchor < 300000
#define KIO_BLOCKS 63           // tail kernel: 63 blocks x 1024 (all co-resident)

// ---- workspace layout (bytes), M = 300000 ----
#define WS_CAND     0           // 12288 u64 composite keys
#define WS_TKSCORE  98304       // 1000 f32
#define WS_TKANCH   102304      // 1000 i32
#define WS_TKLABEL  106304      // 1000 i32
#define WS_BOXES    110304      // 1000 float4
#define WS_OBX      126304      // 1000 float4 (class-offset boxes)
#define WS_AREAS    142304      // 1000 f32
#define WS_MASK     146304      // 1000 * 16 u64 transposed sup mask
#define WS_META     274304      // [0]=bin B, [2]=fast cnt, [3]=fb cnt, [4]=kfb done,
                                // [5]=kfb flag, [6]=kio bar1 cnt, [7]=kio bar1 flag,
                                // [8]=kio bar2 cnt   (all zeroed by 64 B memset)
#define WS_HIST     274368      // HREP * 8192 u32 (zeroed inside k1)
// end = 536,512 B

typedef unsigned long long u64;

__device__ __forceinline__ float sigmoidf_(float x) {
    return 1.0f / (1.0f + expf(-x));
}

// composite key: [50:19]=score bits, [18:0]=(2^19-1-anchor).
// u64 descending == (score desc, anchor asc); (score,anchor) unique.
__device__ __forceinline__ u64 make_key2(unsigned s32, int anchor) {
    return ((u64)s32 << 19) | (unsigned)(ANCH_INV - anchor);
}

// BIN 0 = HIGHEST scores (descending bins): ascending-bin exclusive prefix
// sum = "# elements in higher-score bins" = correct rank base.
__device__ __forceinline__ int key_bin(u64 k) {
    unsigned s32 = (unsigned)(k >> 19);
    int d = (int)(s32 - RBIN_LO);
    if (d < 0) d = 0;
    int b = d >> 9;
    if (b > RBINS - 1) b = RBINS - 1;
    return (RBINS - 1) - b;
}

// row max+argmax over 80 classes with 16 lanes (l = lane & 15), first-max tie
__device__ __forceinline__ void rowmax16(const float4* row, int l,
                                         float& bv, int& bc) {
    float4 v4 = row[l];
    bv = v4.x; bc = l * 4;
    if (v4.y > bv) { bv = v4.y; bc = l * 4 + 1; }
    if (v4.z > bv) { bv = v4.z; bc = l * 4 + 2; }
    if (v4.w > bv) { bv = v4.w; bc = l * 4 + 3; }
    if (l < 4) {
        float4 w4 = row[16 + l];
        int cb = 64 + l * 4;
        if (w4.x > bv) { bv = w4.x; bc = cb; }
        if (w4.y > bv) { bv = w4.y; bc = cb + 1; }
        if (w4.z > bv) { bv = w4.z; bc = cb + 2; }
        if (w4.w > bv) { bv = w4.w; bc = cb + 3; }
    }
    #pragma unroll
    for (int m = 8; m >= 1; m >>= 1) {
        float ov = __shfl_xor(bv, m);
        int oc = __shfl_xor(bc, m);
        if (ov > bv || (ov == bv && oc < bc)) { bv = ov; bc = oc; }
    }
}

// K1 (fast path): coalesced per-lane obj scan (256 anchors/block),
// survivors to LDS queue, 16-lane groups drain queue for cls row-max.
// score>T0 requires sig(obj)>T0^2 (since sig(clsmax)<1) => obj>OBJ_T is a
// strictly looser necessary condition -> candidate set {score>T0} unchanged.
// Also zeroes the fallback histogram (kfb runs after k1 in-stream).
__global__ void __launch_bounds__(256)
k1_scores(const float* __restrict__ obj,
          const float* __restrict__ cls,
          u64* __restrict__ cand,
          int* __restrict__ counter,
          unsigned* __restrict__ hist,
          int M) {
    __shared__ int lcount, lbase, nsurv;
    __shared__ int sanch[256];
    __shared__ float sobj[256];
    __shared__ u64 lkeys[256];
    int t = threadIdx.x;
    if (t == 0) { lcount = 0; nsurv = 0; }
    // zero fallback hist: HREP*NB u32 = 16384 uint4, grid-stride
    for (int i = blockIdx.x * 256 + t; i < (HREP * NB) / 4; i += gridDim.x * 256)
        ((uint4*)hist)[i] = make_uint4(0u, 0u, 0u, 0u);
    __syncthreads();
    int a = blockIdx.x * 256 + t;
    float o = (a < M) ? obj[a] : -1e30f;       // coalesced 1KB/wave
    if (o > OBJ_T) {
        int p = atomicAdd(&nsurv, 1);
        sanch[p] = a; sobj[p] = o;
    }
    __syncthreads();
    int ns = nsurv;                            // ~5.8% of 256 ~= 15 expected
    int grp = t >> 4, l = t & 15;
    for (int s = grp; s < ns; s += 16) {       // uniform per 16-lane group
        int anchor = sanch[s];
        const float4* p = (const float4*)(cls + (size_t)anchor * NCLS);
        float4 v = p[l];
        float m = fmaxf(fmaxf(v.x, v.y), fmaxf(v.z, v.w));
        if (l < 4) {                           // 16-float tail of the row
            float4 w4 = p[16 + l];
            m = fmaxf(m, fmaxf(fmaxf(w4.x, w4.y), fmaxf(w4.z, w4.w)));
        }
        #pragma unroll
        for (int sh = 8; sh >= 1; sh >>= 1)
            m = fmaxf(m, __shfl_xor(m, sh));
        if (l == 0) {
            float score = sqrtf(sigmoidf_(sobj[s]) * sigmoidf_(m));
            if (score > T0) {
                int pos = atomicAdd(&lcount, 1);
                lkeys[pos] = make_key2(__float_as_uint(score), anchor);
            }
        }
    }
    __syncthreads();
    if (t == 0 && lcount > 0) lbase = atomicAdd(counter, lcount);
    __syncthreads();
    int n = lcount;
    if (t < n) {
        int pos = lbase + t;
        if (pos < CAND_CAP) cand[pos] = lkeys[t];
    }
}

// KFB (fallback, gated; fuses old kf+k2+k3 via device-scope barrier):
// phase 1: replicated histogram of all scores.
// last-done block: fold replicas + descending scan -> threshold bin meta[0],
// release flag meta[5]. All blocks spin (all co-resident: 512x256 = 2048 waves
// well under the 8192-wave device capacity).
// phase 2: RECOMPUTE scores (no cross-XCD plain-store traffic) and compact
// all anchors with bin >= B. Hot path: gate-load + immediate exit.
__global__ void __launch_bounds__(256)
kfb_fallback(const float* __restrict__ obj,
             const float* __restrict__ cls,
             unsigned* __restrict__ hist,
             int* __restrict__ meta,
             u64* __restrict__ cand, int M) {
    int C = meta[2];
    if (C >= TOPK_N && C <= CAND_CAP) return;     // fast path succeeded
    int t = threadIdx.x;
    int gw = (blockIdx.x * 256 + t) >> 6;
    int TW = gridDim.x * 4;
    int lane64 = t & 63;
    int g = lane64 >> 4, l = lane64 & 15;
    int rep = blockIdx.x & (HREP - 1);
    // ---- phase 1: histogram ----
    for (int a0 = gw * 4; a0 < M; a0 += TW * 4) {
        int anchor = a0 + g;
        if (anchor >= M) continue;
        const float4* row = (const float4*)(cls + (size_t)anchor * NCLS);
        float bv; int bc;
        rowmax16(row, l, bv, bc);
        if (l == 0) {
            float score = sqrtf(sigmoidf_(obj[anchor]) * sigmoidf_(bv));
            atomicAdd(&hist[(size_t)rep * NB + (__float_as_uint(score) >> 17)], 1u);
        }
    }
    __threadfence();
    __shared__ bool last;
    if (t == 0)
        last = (atomicAdd(meta + 4, 1) == (int)gridDim.x - 1);
    __syncthreads();
    if (last) {
        // ---- folded scan: 256 threads x 32 descending bins each ----
        int lane = t & 63, w = t >> 6;
        int base = NB - 1 - t * 32;
        unsigned bins[32]; unsigned s = 0;
        #pragma unroll
        for (int k = 0; k < 32; ++k) {
            unsigned h = 0;
            for (int r = 0; r < HREP; ++r)
                h += atomicOr(&hist[(size_t)r * NB + base - k], 0u);
            bins[k] = h; s += h;
        }
        unsigned inc = s;
        for (int d = 1; d < 64; d <<= 1) {
            unsigned pv = __shfl_up(inc, d);
            if (lane >= d) inc += pv;
        }
        __shared__ unsigned wsum[4], woff[4];
        if (lane == 63) wsum[w] = inc;
        __syncthreads();
        if (t == 0) {
            unsigned cum = 0;
            for (int i = 0; i < 4; ++i) { woff[i] = cum; cum += wsum[i]; }
        }
        __syncthreads();
        unsigned excl = woff[w] + inc - s;
        if (excl < TOPK_N && excl + s >= TOPK_N) {
            unsigned cum = excl; int b = base;
            #pragma unroll
            for (int k = 0; k < 32; ++k) {
                unsigned h = bins[k];
                if (cum + h >= TOPK_N) { atomicExch(meta + 0, b); break; }
                cum += h; --b;
            }
        }
        __syncthreads();
        __threadfence();
        if (t == 0) atomicExch(meta + 5, 1);      // release
    }
    if (t == 0)
        while (atomicAdd(meta + 5, 0) == 0) { __builtin_amdgcn_s_sleep(8); }
    __syncthreads();
    __threadfence();                              // acquire
    int B = atomicAdd(meta + 0, 0);
    // ---- phase 2: recompute + compact (exact) ----
    for (int a0 = gw * 4; a0 < M; a0 += TW * 4) {
        int anchor = a0 + g;
        if (anchor >= M) continue;
        const float4* row = (const float4*)(cls + (size_t)anchor * NCLS);
        float bv; int bc;
        rowmax16(row, l, bv, bc);
        if (l == 0) {
            float score = sqrtf(sigmoidf_(obj[anchor]) * sigmoidf_(bv));
            unsigned key = __float_as_uint(score);
            if ((int)(key >> 17) >= B) {
                int pos = atomicAdd(meta + 3, 1);
                if (pos < CAND_CAP)
                    cand[pos] = make_key2(key, anchor);
            }
        }
    }
}

// K4: counting-sort rank -> (tkscore, tkanchor). O(C).
__global__ void __launch_bounds__(1024)
k4_rank(const u64* __restrict__ cand,
        const int* __restrict__ meta,
        float* __restrict__ tkscore,
        int* __restrict__ tkanchor) {
    __shared__ u64 sorted[CAND_CAP];        // 98304 B
    __shared__ unsigned hist[RBINS];        // exclusive base after prefix
    __shared__ unsigned cnt[RBINS];
    __shared__ unsigned wsum[16], woff[16];
    int t = threadIdx.x;                    // 1024
    int lane = t & 63, w = t >> 6;
    int Cf = meta[2];
    bool fast = (Cf >= TOPK_N && Cf <= CAND_CAP);
    int C = fast ? Cf : meta[3];
    if (C > CAND_CAP) C = CAND_CAP;
    for (int b = t; b < RBINS; b += 1024) { hist[b] = 0; cnt[b] = 0; }
    __syncthreads();
    u64 keys[12]; int nk = 0;
    for (int i = t; i < C; i += 1024) {
        u64 k = cand[i];
        keys[nk++] = k;
        atomicAdd(&hist[key_bin(k)], 1u);
    }
    __syncthreads();
    unsigned h0 = hist[t * 3], h1 = hist[t * 3 + 1], h2 = hist[t * 3 + 2];
    unsigned s = h0 + h1 + h2;
    unsigned inc = s;
    for (int d = 1; d < 64; d <<= 1) {
        unsigned pv = __shfl_up(inc, d);
        if (lane >= d) inc += pv;
    }
    if (lane == 63) wsum[w] = inc;
    __syncthreads();
    if (t == 0) {
        unsigned cum = 0;
        for (int i = 0; i < 16; ++i) { woff[i] = cum; cum += wsum[i]; }
    }
    __syncthreads();
    unsigned base = woff[w] + inc - s;
    hist[t * 3] = base;
    hist[t * 3 + 1] = base + h0;
    hist[t * 3 + 2] = base + h0 + h1;
    __syncthreads();
    nk = 0;
    for (int i = t; i < C; i += 1024) {
        u64 k = keys[nk++];
        int b = key_bin(k);
        unsigned pos = hist[b] + atomicAdd(&cnt[b], 1u);
        sorted[pos] = k;
    }
    __syncthreads();
    for (int p = t; p < C; p += 1024) {
        u64 k = sorted[p];
        int b = key_bin(k);
        unsigned b0 = hist[b], b1 = b0 + cnt[b];
        int r = (int)b0;
        for (unsigned q = b0; q < b1; ++q) r += (sorted[q] > k);
        if (r < TOPK_N) {
            tkscore[r] = __uint_as_float((unsigned)(k >> 19));
            tkanchor[r] = ANCH_INV - (int)(k & 0x7FFFF);
        }
    }
}

// KIO (fuses old k4b+k5+k6): 63 blocks x 1024 threads, all co-resident
// (63 blocks <= 256 CUs -> each block can sit on its own CU regardless of
// occupancy). Phase A: gather (1000 fully-parallel 16-lane groups).
// Barrier 1 (device-scope atomics + fences). Phase B: IoU with obx/areas
// staged in LDS, 16 rows/block (one per wave). Barrier 2 (arrive-only).
// Phase C: block 0 runs the atomic-free greedy NMS + fused output write.
__global__ void __launch_bounds__(1024)
kio_tail(const float* __restrict__ cls,
         const float4* __restrict__ box,
         const float* __restrict__ tkscore,
         const int* __restrict__ tkanchor,
         int* __restrict__ tklabel,
         float4* __restrict__ boxes_k,
         float4* __restrict__ obx,
         float* __restrict__ areas,
         u64* __restrict__ mask,
         int* __restrict__ meta,
         float* __restrict__ out) {
    __shared__ float4 sobx[TOPK_N];         // 16000 B
    __shared__ float  sarea[TOPK_N];        // 4000 B
    __shared__ u64 kept_s[16], dec_s[16];
    int t = threadIdx.x, bid = blockIdx.x;
    int nblk = gridDim.x;
    // ---- phase A: per-rank gather (argmax over 80 + box/obx/area) ----
    int G = bid * 64 + (t >> 4), l16 = t & 15;
    if (G < TOPK_N) {
        int anchor = tkanchor[G];
        const float4* row = (const float4*)(cls + (size_t)anchor * NCLS);
        float bv; int bc;
        rowmax16(row, l16, bv, bc);
        if (l16 == 0) {
            tklabel[G] = bc;
            float4 b = box[anchor];
            boxes_k[G] = b;
            float off = (float)bc * 4096.0f;
            float4 ob = make_float4(b.x + off, b.y + off, b.z + off, b.w + off);
            obx[G] = ob;
            areas[G] = fmaxf(ob.z - ob.x, 0.0f) * fmaxf(ob.w - ob.y, 0.0f);
        }
    }
    // ---- barrier 1: full (release writes, acquire others') ----
    __syncthreads();
    __threadfence();
    if (t == 0) {
        if (atomicAdd(meta + 6, 1) == nblk - 1)
            atomicExch(meta + 7, 1);
        while (atomicAdd(meta + 7, 0) == 0) { __builtin_amdgcn_s_sleep(8); }
    }
    __syncthreads();
    __threadfence();
    // ---- phase B: stage all obx/areas to LDS, IoU rows bid*16+w ----
    for (int j = t; j < TOPK_N; j += 1024) { sobx[j] = obx[j]; sarea[j] = areas[j]; }
    __syncthreads();
    int w = t >> 6, lane = t & 63;
    int i = bid * 16 + w;
    if (i < TOPK_N) {
        float4 bi = sobx[i];
        float ai = sarea[i];
        #pragma unroll 4
        for (int q = 0; q < 16; ++q) {
            int c = q * 64 + lane;
            bool bit = false;
            if (c < i) {
                float4 bc = sobx[c];
                float xx1 = fmaxf(bi.x, bc.x), yy1 = fmaxf(bi.y, bc.y);
                float xx2 = fminf(bi.z, bc.z), yy2 = fminf(bi.w, bc.w);
                float inter = fmaxf(xx2 - xx1, 0.0f) * fmaxf(yy2 - yy1, 0.0f);
                float iou = inter / (ai + sarea[c] - inter + 1e-9f);
                bit = iou > 0.5f;
            }
            u64 bal = __ballot(bit);
            if (lane == 0) mask[(size_t)i * 16 + q] = bal;
        }
    }
    // ---- barrier 2: arrive-only; block 0 waits then runs NMS ----
    __syncthreads();
    __threadfence();
    if (bid != 0) {
        if (t == 0) atomicAdd(meta + 8, 1);
        return;
    }
    if (t == 0) {
        atomicAdd(meta + 8, 1);
        while (atomicAdd(meta + 8, 0) < nblk) { __builtin_amdgcn_s_sleep(8); }
    }
    __syncthreads();
    __threadfence();
    // ---- phase C: atomic-free parallel exact greedy NMS + output ----
    bool active = t < TOPK_N;
    u64 sup[16];
    float sc = 0.0f;
    if (active) {
        #pragma unroll
        for (int q = 0; q < 16; ++q) sup[q] = mask[(size_t)t * 16 + q];
        sc = tkscore[t];
    } else {
        #pragma unroll
        for (int q = 0; q < 16; ++q) sup[q] = 0ULL;
    }
    bool conf = active && (sc > 0.001f);
    bool mydec = !conf;
    bool mykept = false;
    u64 db = __ballot(mydec), kb = __ballot(mykept);
    if (lane == 0) { dec_s[w] = db; kept_s[w] = kb; }
    __syncthreads();
    for (int round = 0; round < TOPK_N; ++round) {
        if (!mydec) {
            u64 pend = 0;
            #pragma unroll
            for (int q = 0; q < 16; ++q) pend |= sup[q] & ~dec_s[q];
            if (pend == 0ULL) {
                u64 kk = 0;
                #pragma unroll
                for (int q = 0; q < 16; ++q) kk |= sup[q] & kept_s[q];
                mydec = true; mykept = (kk == 0ULL);
            }
        }
        __syncthreads();
        db = __ballot(mydec); kb = __ballot(mykept);
        if (lane == 0) { dec_s[w] = db; kept_s[w] = kb; }
        __syncthreads();
        u64 a = ~0ULL;
        #pragma unroll
        for (int q = 0; q < 16; ++q) a &= dec_s[q];
        if (a == ~0ULL) break;
    }
    if (active) {
        float k = mykept ? 1.0f : 0.0f;
        float4 b = boxes_k[t];
        out[t * 5 + 0] = sc * k;
        out[t * 5 + 1] = b.x * k;
        out[t * 5 + 2] = b.y * k;
        out[t * 5 + 3] = b.z * k;
        out[t * 5 + 4] = b.w * k;
        out[5 * TOPK_N + t] = (float)tklabel[t];
        out[6 * TOPK_N + t] = k;
    }
}

extern "C" void kernel_launch(void* const* d_in, const int* in_sizes, int n_in,
                              void* d_out, int out_size, void* d_ws, size_t ws_size,
                              hipStream_t stream) {
    const float* obj = (const float*)d_in[0];
    const float* cls = (const float*)d_in[1];
    const float* box = (const float*)d_in[2];
    float* out = (float*)d_out;
    char* ws = (char*)d_ws;
    int M = in_sizes[0];   // 300000

    u64*      cand    = (u64*)(ws + WS_CAND);
    float*    tkscore = (float*)(ws + WS_TKSCORE);
    int*      tkanch  = (int*)(ws + WS_TKANCH);
    int*      tklabel = (int*)(ws + WS_TKLABEL);
    float4*   boxes_k = (float4*)(ws + WS_BOXES);
    float4*   obx     = (float4*)(ws + WS_OBX);
    float*    areas   = (float*)(ws + WS_AREAS);
    u64*      mask    = (u64*)(ws + WS_MASK);
    int*      meta    = (int*)(ws + WS_META);
    unsigned* hist    = (unsigned*)(ws + WS_HIST);

    // zero meta only (64 B); fallback hist is zeroed inside k1 (runs before kfb)
    hipMemsetAsync(ws + WS_META, 0, 64, stream);

    k1_scores<<<(M + 255) / 256, 256, 0, stream>>>(obj, cls, cand, meta + 2, hist, M);
    kfb_fallback<<<512, 256, 0, stream>>>(obj, cls, hist, meta, cand, M);
    k4_rank<<<1, 1024, 0, stream>>>(cand, meta, tkscore, tkanch);
    kio_tail<<<KIO_BLOCKS, 1024, 0, stream>>>(cls, (const float4*)box, tkscore,
                                              tkanch, tklabel, boxes_k, obx, areas,
                                              mask, meta, out);
}

// Round 5
// 165.921 us; speedup vs baseline: 1.2843x; 1.2843x over previous
//
#include <hip/hip_runtime.h>
#include <hip/hip_bf16.h>
#include <math.h>

#define NCLS 80
#define TOPK_N 1000
#define CAND_CAP 12288
#define T0 0.91f                // fast-path score threshold (exactness gated)
#define OBJ_T 1.55f             // obj pre-filter: sig(1.55)=0.8249 < T0^2=0.8281
                                // score>T0 ==> sig(obj)>T0^2 ==> obj>OBJ_T (safe margin)
#define NB 8192                 // fallback histogram bins = key >> 17
#define HREP 8                  // fallback histogram replicas
#define RBINS 3072              // rank bins (k4 counting sort)
#define RBIN_LO 0x3F680000u     // float bits of ~0.90625
#define ANCH_INV 524287         // 2^19-1, anchor < 300000

// ---- workspace layout (bytes), M = 300000 ----
#define WS_CAND     0           // 12288 u64 composite keys
#define WS_TKSCORE  98304       // 1000 f32
#define WS_TKANCH   102304      // 1000 i32
#define WS_TKLABEL  106304      // 1000 i32
#define WS_BOXES    110304      // 1000 float4
#define WS_OBX      126304      // 1000 float4 (class-offset boxes)
#define WS_AREAS    142304      // 1000 f32
#define WS_MASK     146304      // 1000 * 16 u64 transposed sup mask
#define WS_META     274304      // [0]=bin B, [2]=fast cnt, [3]=fb cnt, [4]=kfb done,
                                // [5]=kfb flag   (all zeroed by 64 B memset)
#define WS_HIST     274368      // HREP * 8192 u32 (zeroed inside k1)
// end = 536,512 B

typedef unsigned long long u64;

__device__ __forceinline__ float sigmoidf_(float x) {
    return 1.0f / (1.0f + expf(-x));
}

// composite key: [50:19]=score bits, [18:0]=(2^19-1-anchor).
// u64 descending == (score desc, anchor asc); (score,anchor) unique.
__device__ __forceinline__ u64 make_key2(unsigned s32, int anchor) {
    return ((u64)s32 << 19) | (unsigned)(ANCH_INV - anchor);
}

// BIN 0 = HIGHEST scores (descending bins): ascending-bin exclusive prefix
// sum = "# elements in higher-score bins" = correct rank base.
__device__ __forceinline__ int key_bin(u64 k) {
    unsigned s32 = (unsigned)(k >> 19);
    int d = (int)(s32 - RBIN_LO);
    if (d < 0) d = 0;
    int b = d >> 9;
    if (b > RBINS - 1) b = RBINS - 1;
    return (RBINS - 1) - b;
}

// row max+argmax over 80 classes with 16 lanes (l = lane & 15), first-max tie
__device__ __forceinline__ void rowmax16(const float4* row, int l,
                                         float& bv, int& bc) {
    float4 v4 = row[l];
    bv = v4.x; bc = l * 4;
    if (v4.y > bv) { bv = v4.y; bc = l * 4 + 1; }
    if (v4.z > bv) { bv = v4.z; bc = l * 4 + 2; }
    if (v4.w > bv) { bv = v4.w; bc = l * 4 + 3; }
    if (l < 4) {
        float4 w4 = row[16 + l];
        int cb = 64 + l * 4;
        if (w4.x > bv) { bv = w4.x; bc = cb; }
        if (w4.y > bv) { bv = w4.y; bc = cb + 1; }
        if (w4.z > bv) { bv = w4.z; bc = cb + 2; }
        if (w4.w > bv) { bv = w4.w; bc = cb + 3; }
    }
    #pragma unroll
    for (int m = 8; m >= 1; m >>= 1) {
        float ov = __shfl_xor(bv, m);
        int oc = __shfl_xor(bc, m);
        if (ov > bv || (ov == bv && oc < bc)) { bv = ov; bc = oc; }
    }
}

// K1 (fast path): coalesced per-lane obj scan (256 anchors/block),
// survivors to LDS queue, 16-lane groups drain queue for cls row-max.
// score>T0 requires sig(obj)>T0^2 (since sig(clsmax)<1) => obj>OBJ_T is a
// strictly looser necessary condition -> candidate set {score>T0} unchanged.
// Also zeroes the fallback histogram (kfb runs after k1 in-stream).
__global__ void __launch_bounds__(256)
k1_scores(const float* __restrict__ obj,
          const float* __restrict__ cls,
          u64* __restrict__ cand,
          int* __restrict__ counter,
          unsigned* __restrict__ hist,
          int M) {
    __shared__ int lcount, lbase, nsurv;
    __shared__ int sanch[256];
    __shared__ float sobj[256];
    __shared__ u64 lkeys[256];
    int t = threadIdx.x;
    if (t == 0) { lcount = 0; nsurv = 0; }
    // zero fallback hist: HREP*NB u32 = 16384 uint4, grid-stride
    for (int i = blockIdx.x * 256 + t; i < (HREP * NB) / 4; i += gridDim.x * 256)
        ((uint4*)hist)[i] = make_uint4(0u, 0u, 0u, 0u);
    __syncthreads();
    int a = blockIdx.x * 256 + t;
    float o = (a < M) ? obj[a] : -1e30f;       // coalesced 1KB/wave
    if (o > OBJ_T) {
        int p = atomicAdd(&nsurv, 1);
        sanch[p] = a; sobj[p] = o;
    }
    __syncthreads();
    int ns = nsurv;                            // ~5.8% of 256 ~= 15 expected
    int grp = t >> 4, l = t & 15;
    for (int s = grp; s < ns; s += 16) {       // uniform per 16-lane group
        int anchor = sanch[s];
        const float4* p = (const float4*)(cls + (size_t)anchor * NCLS);
        float4 v = p[l];
        float m = fmaxf(fmaxf(v.x, v.y), fmaxf(v.z, v.w));
        if (l < 4) {                           // 16-float tail of the row
            float4 w4 = p[16 + l];
            m = fmaxf(m, fmaxf(fmaxf(w4.x, w4.y), fmaxf(w4.z, w4.w)));
        }
        #pragma unroll
        for (int sh = 8; sh >= 1; sh >>= 1)
            m = fmaxf(m, __shfl_xor(m, sh));
        if (l == 0) {
            float score = sqrtf(sigmoidf_(sobj[s]) * sigmoidf_(m));
            if (score > T0) {
                int pos = atomicAdd(&lcount, 1);
                lkeys[pos] = make_key2(__float_as_uint(score), anchor);
            }
        }
    }
    __syncthreads();
    if (t == 0 && lcount > 0) lbase = atomicAdd(counter, lcount);
    __syncthreads();
    int n = lcount;
    if (t < n) {
        int pos = lbase + t;
        if (pos < CAND_CAP) cand[pos] = lkeys[t];
    }
}

// KFB (fallback, gated; fuses old kf+k2+k3). Hot path: ONE gate load
// (coherent at kernel start) -> immediate exit, no fences executed.
// Fallback path (never taken on this data, kept exact): histogram, last-done
// block folds+scans -> bin B, spin-release, recompute+compact.
__global__ void __launch_bounds__(256)
kfb_fallback(const float* __restrict__ obj,
             const float* __restrict__ cls,
             unsigned* __restrict__ hist,
             int* __restrict__ meta,
             u64* __restrict__ cand, int M) {
    int C = meta[2];
    if (C >= TOPK_N && C <= CAND_CAP) return;     // fast path succeeded
    int t = threadIdx.x;
    int gw = (blockIdx.x * 256 + t) >> 6;
    int TW = gridDim.x * 4;
    int lane64 = t & 63;
    int g = lane64 >> 4, l = lane64 & 15;
    int rep = blockIdx.x & (HREP - 1);
    // ---- phase 1: histogram ----
    for (int a0 = gw * 4; a0 < M; a0 += TW * 4) {
        int anchor = a0 + g;
        if (anchor >= M) continue;
        const float4* row = (const float4*)(cls + (size_t)anchor * NCLS);
        float bv; int bc;
        rowmax16(row, l, bv, bc);
        if (l == 0) {
            float score = sqrtf(sigmoidf_(obj[anchor]) * sigmoidf_(bv));
            atomicAdd(&hist[(size_t)rep * NB + (__float_as_uint(score) >> 17)], 1u);
        }
    }
    __threadfence();
    __shared__ bool last;
    if (t == 0)
        last = (atomicAdd(meta + 4, 1) == (int)gridDim.x - 1);
    __syncthreads();
    if (last) {
        // ---- folded scan: 256 threads x 32 descending bins each ----
        int lane = t & 63, w = t >> 6;
        int base = NB - 1 - t * 32;
        unsigned bins[32]; unsigned s = 0;
        #pragma unroll
        for (int k = 0; k < 32; ++k) {
            unsigned h = 0;
            for (int r = 0; r < HREP; ++r)
                h += atomicOr(&hist[(size_t)r * NB + base - k], 0u);
            bins[k] = h; s += h;
        }
        unsigned inc = s;
        for (int d = 1; d < 64; d <<= 1) {
            unsigned pv = __shfl_up(inc, d);
            if (lane >= d) inc += pv;
        }
        __shared__ unsigned wsum[4], woff[4];
        if (lane == 63) wsum[w] = inc;
        __syncthreads();
        if (t == 0) {
            unsigned cum = 0;
            for (int i = 0; i < 4; ++i) { woff[i] = cum; cum += wsum[i]; }
        }
        __syncthreads();
        unsigned excl = woff[w] + inc - s;
        if (excl < TOPK_N && excl + s >= TOPK_N) {
            unsigned cum = excl; int b = base;
            #pragma unroll
            for (int k = 0; k < 32; ++k) {
                unsigned h = bins[k];
                if (cum + h >= TOPK_N) { atomicExch(meta + 0, b); break; }
                cum += h; --b;
            }
        }
        __syncthreads();
        __threadfence();
        if (t == 0) atomicExch(meta + 5, 1);      // release
    }
    if (t == 0)
        while (atomicAdd(meta + 5, 0) == 0) { __builtin_amdgcn_s_sleep(8); }
    __syncthreads();
    __threadfence();                              // acquire
    int B = atomicAdd(meta + 0, 0);
    // ---- phase 2: recompute + compact (exact) ----
    for (int a0 = gw * 4; a0 < M; a0 += TW * 4) {
        int anchor = a0 + g;
        if (anchor >= M) continue;
        const float4* row = (const float4*)(cls + (size_t)anchor * NCLS);
        float bv; int bc;
        rowmax16(row, l, bv, bc);
        if (l == 0) {
            float score = sqrtf(sigmoidf_(obj[anchor]) * sigmoidf_(bv));
            unsigned key = __float_as_uint(score);
            if ((int)(key >> 17) >= B) {
                int pos = atomicAdd(meta + 3, 1);
                if (pos < CAND_CAP)
                    cand[pos] = make_key2(key, anchor);
            }
        }
    }
}

// K4: counting-sort rank -> (tkscore, tkanchor). O(C).
__global__ void __launch_bounds__(1024)
k4_rank(const u64* __restrict__ cand,
        const int* __restrict__ meta,
        float* __restrict__ tkscore,
        int* __restrict__ tkanchor) {
    __shared__ u64 sorted[CAND_CAP];        // 98304 B
    __shared__ unsigned hist[RBINS];        // exclusive base after prefix
    __shared__ unsigned cnt[RBINS];
    __shared__ unsigned wsum[16], woff[16];
    int t = threadIdx.x;                    // 1024
    int lane = t & 63, w = t >> 6;
    int Cf = meta[2];
    bool fast = (Cf >= TOPK_N && Cf <= CAND_CAP);
    int C = fast ? Cf : meta[3];
    if (C > CAND_CAP) C = CAND_CAP;
    for (int b = t; b < RBINS; b += 1024) { hist[b] = 0; cnt[b] = 0; }
    __syncthreads();
    u64 keys[12]; int nk = 0;
    for (int i = t; i < C; i += 1024) {
        u64 k = cand[i];
        keys[nk++] = k;
        atomicAdd(&hist[key_bin(k)], 1u);
    }
    __syncthreads();
    unsigned h0 = hist[t * 3], h1 = hist[t * 3 + 1], h2 = hist[t * 3 + 2];
    unsigned s = h0 + h1 + h2;
    unsigned inc = s;
    for (int d = 1; d < 64; d <<= 1) {
        unsigned pv = __shfl_up(inc, d);
        if (lane >= d) inc += pv;
    }
    if (lane == 63) wsum[w] = inc;
    __syncthreads();
    if (t == 0) {
        unsigned cum = 0;
        for (int i = 0; i < 16; ++i) { woff[i] = cum; cum += wsum[i]; }
    }
    __syncthreads();
    unsigned base = woff[w] + inc - s;
    hist[t * 3] = base;
    hist[t * 3 + 1] = base + h0;
    hist[t * 3 + 2] = base + h0 + h1;
    __syncthreads();
    nk = 0;
    for (int i = t; i < C; i += 1024) {
        u64 k = keys[nk++];
        int b = key_bin(k);
        unsigned pos = hist[b] + atomicAdd(&cnt[b], 1u);
        sorted[pos] = k;
    }
    __syncthreads();
    for (int p = t; p < C; p += 1024) {
        u64 k = sorted[p];
        int b = key_bin(k);
        unsigned b0 = hist[b], b1 = b0 + cnt[b];
        int r = (int)b0;
        for (unsigned q = b0; q < b1; ++q) r += (sorted[q] > k);
        if (r < TOPK_N) {
            tkscore[r] = __uint_as_float((unsigned)(k >> 19));
            tkanchor[r] = ANCH_INV - (int)(k & 0x7FFFF);
        }
    }
}

// K4b: per-rank label recompute (argmax over 80) + box/obx/area gather.
// 16 lanes per rank, 16 ranks per block.
__global__ void __launch_bounds__(256)
k4b_gather(const float* __restrict__ cls,
           const float4* __restrict__ box,
           const int* __restrict__ tkanchor,
           int* __restrict__ tklabel,
           float4* __restrict__ boxes_k,
           float4* __restrict__ obx,
           float* __restrict__ areas) {
    int grp = threadIdx.x >> 4, l = threadIdx.x & 15;
    int r = blockIdx.x * 16 + grp;
    if (r >= TOPK_N) return;
    int anchor = tkanchor[r];
    const float4* row = (const float4*)(cls + (size_t)anchor * NCLS);
    float bv; int bc;
    rowmax16(row, l, bv, bc);
    if (l == 0) {
        tklabel[r] = bc;
        float4 b = box[anchor];
        boxes_k[r] = b;
        float off = (float)bc * 4096.0f;
        float4 ob = make_float4(b.x + off, b.y + off, b.z + off, b.w + off);
        obx[r] = ob;
        areas[r] = fmaxf(ob.z - ob.x, 0.0f) * fmaxf(ob.w - ob.y, 0.0f);
    }
}

// K5: transposed suppression mask with block-local LDS staging of all
// obx/areas (20 KB); 16 rows/block (one per wave), 63 blocks.
__global__ void __launch_bounds__(1024)
k5_iou(const float4* __restrict__ obx,
       const float* __restrict__ areas,
       u64* __restrict__ mask) {
    __shared__ float4 sobx[TOPK_N];         // 16000 B
    __shared__ float  sarea[TOPK_N];        // 4000 B
    int t = threadIdx.x;
    for (int j = t; j < TOPK_N; j += 1024) { sobx[j] = obx[j]; sarea[j] = areas[j]; }
    __syncthreads();
    int w = t >> 6, lane = t & 63;
    int i = blockIdx.x * 16 + w;
    if (i >= TOPK_N) return;
    float4 bi = sobx[i];
    float ai = sarea[i];
    #pragma unroll 4
    for (int q = 0; q < 16; ++q) {
        int c = q * 64 + lane;
        bool bit = false;
        if (c < i) {
            float4 bc = sobx[c];
            float xx1 = fmaxf(bi.x, bc.x), yy1 = fmaxf(bi.y, bc.y);
            float xx2 = fminf(bi.z, bc.z), yy2 = fminf(bi.w, bc.w);
            float inter = fmaxf(xx2 - xx1, 0.0f) * fmaxf(yy2 - yy1, 0.0f);
            float iou = inter / (ai + sarea[c] - inter + 1e-9f);
            bit = iou > 0.5f;
        }
        u64 bal = __ballot(bit);
        if (lane == 0) mask[(size_t)i * 16 + q] = bal;
    }
}

// K6: atomic-free parallel exact greedy NMS + fused output write.
__global__ void __launch_bounds__(1024)
k6_nms(const float* __restrict__ tkscore,
       const u64* __restrict__ mask,
       const int* __restrict__ tklabel,
       const float4* __restrict__ boxes_k,
       float* __restrict__ out) {
    __shared__ u64 kept_s[16], dec_s[16];
    int t = threadIdx.x, w = t >> 6, lane = t & 63;
    bool active = t < TOPK_N;
    u64 sup[16];
    float sc = 0.0f;
    if (active) {
        #pragma unroll
        for (int q = 0; q < 16; ++q) sup[q] = mask[(size_t)t * 16 + q];
        sc = tkscore[t];
    } else {
        #pragma unroll
        for (int q = 0; q < 16; ++q) sup[q] = 0ULL;
    }
    bool conf = active && (sc > 0.001f);
    bool mydec = !conf;
    bool mykept = false;
    u64 db = __ballot(mydec), kb = __ballot(mykept);
    if (lane == 0) { dec_s[w] = db; kept_s[w] = kb; }
    __syncthreads();
    for (int round = 0; round < TOPK_N; ++round) {
        if (!mydec) {
            u64 pend = 0;
            #pragma unroll
            for (int q = 0; q < 16; ++q) pend |= sup[q] & ~dec_s[q];
            if (pend == 0ULL) {
                u64 kk = 0;
                #pragma unroll
                for (int q = 0; q < 16; ++q) kk |= sup[q] & kept_s[q];
                mydec = true; mykept = (kk == 0ULL);
            }
        }
        __syncthreads();
        db = __ballot(mydec); kb = __ballot(mykept);
        if (lane == 0) { dec_s[w] = db; kept_s[w] = kb; }
        __syncthreads();
        u64 a = ~0ULL;
        #pragma unroll
        for (int q = 0; q < 16; ++q) a &= dec_s[q];
        if (a == ~0ULL) break;
    }
    if (active) {
        float k = mykept ? 1.0f : 0.0f;
        float4 b = boxes_k[t];
        out[t * 5 + 0] = sc * k;
        out[t * 5 + 1] = b.x * k;
        out[t * 5 + 2] = b.y * k;
        out[t * 5 + 3] = b.z * k;
        out[t * 5 + 4] = b.w * k;
        out[5 * TOPK_N + t] = (float)tklabel[t];
        out[6 * TOPK_N + t] = k;
    }
}

extern "C" void kernel_launch(void* const* d_in, const int* in_sizes, int n_in,
                              void* d_out, int out_size, void* d_ws, size_t ws_size,
                              hipStream_t stream) {
    const float* obj = (const float*)d_in[0];
    const float* cls = (const float*)d_in[1];
    const float* box = (const float*)d_in[2];
    float* out = (float*)d_out;
    char* ws = (char*)d_ws;
    int M = in_sizes[0];   // 300000

    u64*      cand    = (u64*)(ws + WS_CAND);
    float*    tkscore = (float*)(ws + WS_TKSCORE);
    int*      tkanch  = (int*)(ws + WS_TKANCH);
    int*      tklabel = (int*)(ws + WS_TKLABEL);
    float4*   boxes_k = (float4*)(ws + WS_BOXES);
    float4*   obx     = (float4*)(ws + WS_OBX);
    float*    areas   = (float*)(ws + WS_AREAS);
    u64*      mask    = (u64*)(ws + WS_MASK);
    int*      meta    = (int*)(ws + WS_META);
    unsigned* hist    = (unsigned*)(ws + WS_HIST);

    // zero meta only (64 B); fallback hist is zeroed inside k1 (runs before kfb)
    hipMemsetAsync(ws + WS_META, 0, 64, stream);

    k1_scores<<<(M + 255) / 256, 256, 0, stream>>>(obj, cls, cand, meta + 2, hist, M);
    kfb_fallback<<<512, 256, 0, stream>>>(obj, cls, hist, meta, cand, M);
    k4_rank<<<1, 1024, 0, stream>>>(cand, meta, tkscore, tkanch);
    k4b_gather<<<(TOPK_N + 15) / 16, 256, 0, stream>>>(cls, (const float4*)box,
                                                       tkanch, tklabel, boxes_k, obx, areas);
    k5_iou<<<63, 1024, 0, stream>>>(obx, areas, mask);
    k6_nms<<<1, 1024, 0, stream>>>(tkscore, mask, tklabel, boxes_k, out);
}